// Round 1
// baseline (543.531 us; speedup 1.0000x reference)
//
#include <hip/hip_runtime.h>

// IntraCellularAttention: B=1024, D_INNER=4096, D_STATE=16, D_ATTN=16
// out[b,d,s] = h[b,d,s] + gate * sum_t attn[b,s,t] * h[b,d,t]
// attn = softmax_t( (Q K^T)[s,t] * 0.25 ),  Q[s,a] = sum_d h[b,d,s] Wq[a,d]

constexpr int DI = 4096;
constexpr int DS = 16;

__global__ __launch_bounds__(256) void ica_fused(
    const float* __restrict__ h,
    const float* __restrict__ Wq,
    const float* __restrict__ Wk,
    const float* __restrict__ gate,
    float* __restrict__ out)
{
    const int b   = blockIdx.x;
    const int tid = threadIdx.x;
    const float* __restrict__ hbase = h   + (size_t)b * (DI * DS);
    float*       __restrict__ obase = out + (size_t)b * (DI * DS);

    __shared__ float Qs[DS][20];   // [s][a], padded
    __shared__ float Ks[DS][20];   // [t][a]
    __shared__ float Ms[DS][20];   // [t][s] = delta(s,t) + g*attn[s][t]

    // ---------------- Phase 1: Q, K ----------------
    // thread: a = tid>>4 (0..15), s = tid&15
    {
        const int a = tid >> 4;
        const int s = tid & 15;
        const float* __restrict__ wq = Wq + (size_t)a * DI;
        const float* __restrict__ wk = Wk + (size_t)a * DI;
        float q0 = 0.f, q1 = 0.f, k0 = 0.f, k1 = 0.f;
        for (int d = 0; d < DI; d += 8) {
            float4 wqa = *(const float4*)(wq + d);
            float4 wqb = *(const float4*)(wq + d + 4);
            float4 wka = *(const float4*)(wk + d);
            float4 wkb = *(const float4*)(wk + d + 4);
            float h0 = hbase[(d + 0) * DS + s];
            float h1 = hbase[(d + 1) * DS + s];
            float h2 = hbase[(d + 2) * DS + s];
            float h3 = hbase[(d + 3) * DS + s];
            float h4 = hbase[(d + 4) * DS + s];
            float h5 = hbase[(d + 5) * DS + s];
            float h6 = hbase[(d + 6) * DS + s];
            float h7 = hbase[(d + 7) * DS + s];
            q0 = fmaf(h0, wqa.x, q0); q0 = fmaf(h1, wqa.y, q0);
            q0 = fmaf(h2, wqa.z, q0); q0 = fmaf(h3, wqa.w, q0);
            q1 = fmaf(h4, wqb.x, q1); q1 = fmaf(h5, wqb.y, q1);
            q1 = fmaf(h6, wqb.z, q1); q1 = fmaf(h7, wqb.w, q1);
            k0 = fmaf(h0, wka.x, k0); k0 = fmaf(h1, wka.y, k0);
            k0 = fmaf(h2, wka.z, k0); k0 = fmaf(h3, wka.w, k0);
            k1 = fmaf(h4, wkb.x, k1); k1 = fmaf(h5, wkb.y, k1);
            k1 = fmaf(h6, wkb.z, k1); k1 = fmaf(h7, wkb.w, k1);
        }
        Qs[s][a] = q0 + q1;
        Ks[s][a] = k0 + k1;
    }
    __syncthreads();

    // ---------------- Phase 2: scores + softmax + fold gate ----------------
    const float g = gate[0];
    {
        const int ss = tid >> 4;   // s (query slot)
        const int tt = tid & 15;   // t (key slot)
        float sc = 0.f;
        #pragma unroll
        for (int a4 = 0; a4 < 16; a4 += 4) {
            float4 qv = *(const float4*)&Qs[ss][a4];
            float4 kv = *(const float4*)&Ks[tt][a4];
            sc = fmaf(qv.x, kv.x, sc);
            sc = fmaf(qv.y, kv.y, sc);
            sc = fmaf(qv.z, kv.z, sc);
            sc = fmaf(qv.w, kv.w, sc);
        }
        sc *= 0.25f;  // D_ATTN^-0.5

        // softmax over tt within each 16-lane group (same ss)
        float m = sc;
        #pragma unroll
        for (int o = 8; o > 0; o >>= 1) m = fmaxf(m, __shfl_xor(m, o, 16));
        float e = __expf(sc - m);
        float sm = e;
        #pragma unroll
        for (int o = 8; o > 0; o >>= 1) sm += __shfl_xor(sm, o, 16);
        float attn = e / sm;

        // M[t][s] = delta(s,t) + g * attn[s][t]
        Ms[tt][ss] = ((ss == tt) ? 1.f : 0.f) + g * attn;
    }
    __syncthreads();

    // ---------------- Phase 3: out = H * M  (+residual folded in M) ------
    // thread: sq = tid&3 (s-quad), row = tid>>2 (+64 stride)
    {
        const int sq = tid & 3;
        const int r0 = tid >> 2;
        float4 M4[16];
        #pragma unroll
        for (int tp = 0; tp < 16; ++tp)
            M4[tp] = *(const float4*)&Ms[tp][sq * 4];

        for (int r = r0; r < DI; r += 64) {
            const float4* __restrict__ hr = (const float4*)(hbase + (size_t)r * DS);
            float4 ha = hr[0];
            float4 hc = hr[1];
            float4 he = hr[2];
            float4 hg = hr[3];
            float4 acc; acc.x = acc.y = acc.z = acc.w = 0.f;
            #define ACC4(hs, mm) \
                acc.x = fmaf(hs, mm.x, acc.x); \
                acc.y = fmaf(hs, mm.y, acc.y); \
                acc.z = fmaf(hs, mm.z, acc.z); \
                acc.w = fmaf(hs, mm.w, acc.w);
            ACC4(ha.x, M4[0]);  ACC4(ha.y, M4[1]);
            ACC4(ha.z, M4[2]);  ACC4(ha.w, M4[3]);
            ACC4(hc.x, M4[4]);  ACC4(hc.y, M4[5]);
            ACC4(hc.z, M4[6]);  ACC4(hc.w, M4[7]);
            ACC4(he.x, M4[8]);  ACC4(he.y, M4[9]);
            ACC4(he.z, M4[10]); ACC4(he.w, M4[11]);
            ACC4(hg.x, M4[12]); ACC4(hg.y, M4[13]);
            ACC4(hg.z, M4[14]); ACC4(hg.w, M4[15]);
            #undef ACC4
            *(float4*)(obase + (size_t)r * DS + sq * 4) = acc;
        }
    }
}

extern "C" void kernel_launch(void* const* d_in, const int* in_sizes, int n_in,
                              void* d_out, int out_size, void* d_ws, size_t ws_size,
                              hipStream_t stream) {
    const float* h    = (const float*)d_in[0];
    const float* Wq   = (const float*)d_in[1];
    const float* Wk   = (const float*)d_in[2];
    const float* gate = (const float*)d_in[3];
    float* out = (float*)d_out;
    (void)in_sizes; (void)n_in; (void)out_size; (void)d_ws; (void)ws_size;

    ica_fused<<<1024, 256, 0, stream>>>(h, Wq, Wk, gate, out);
}

// Round 2
// 446.671 us; speedup vs baseline: 1.2168x; 1.2168x over previous
//
#include <hip/hip_runtime.h>

// IntraCellularAttention: B=1024, D_INNER=4096, D_STATE=16, D_ATTN=16
// out[b,d,s] = h[b,d,s] + gate * sum_t attn[b,s,t] * h[b,d,t]
// attn[s,t] = softmax_t( (Q K^T)[s,t] * 0.25 ),  Q[s,a] = sum_d h[b,d,s] Wq[a,d]
//
// One block per batch, 256 threads (4 waves). VGPR must stay <=128 so all
// 4 blocks/CU are resident (4 waves/SIMD cap at 128 VGPR).

constexpr int DI = 4096;
constexpr int DS = 16;
constexpr int CHUNK = 64;              // d-rows staged per iteration
constexpr int NCHUNK = DI / CHUNK;     // 64
constexpr int HS_STRIDE = 68;          // 16B-aligned rows (68*4B=272B=17*16B), 2-way banks

__global__ __launch_bounds__(256) void ica_fused(
    const float* __restrict__ h,
    const float* __restrict__ Wq,
    const float* __restrict__ Wk,
    const float* __restrict__ gate,
    float* __restrict__ out)
{
    const int b   = blockIdx.x;
    const int tid = threadIdx.x;
    const float* __restrict__ hbase = h   + (size_t)b * (DI * DS);
    float*       __restrict__ obase = out + (size_t)b * (DI * DS);

    __shared__ float hs[2][DS][HS_STRIDE];  // transposed h chunk: hs[buf][s][dd]
    __shared__ float Qs[DS][20];            // [s][a]
    __shared__ float Ks[DS][20];            // [t][a]
    __shared__ float Ms[DS][20];            // [t][s] = delta(s,t) + g*attn[s][t]

    // ---------------- Phase 1: Q, K (coalesced, LDS-staged) ----------------
    // Load role:  thread loads float4 = h[d][s0..s0+3], d=c*64+(tid>>2), s0=4*(tid&3)
    // Compute role: thread (a = tid>>4, s = tid&15) accumulates q,k over all d.
    {
        const int dd_ld = tid >> 2;         // 0..63: row-in-chunk this thread stages
        const int s0    = (tid & 3) * 4;    // s-offset of the staged float4
        const int a     = tid >> 4;         // 0..15
        const int s     = tid & 15;         // 0..15
        const float* __restrict__ wqp = Wq + (size_t)a * DI;
        const float* __restrict__ wkp = Wk + (size_t)a * DI;
        const float4* __restrict__ h4 = (const float4*)hbase;

        float qacc = 0.f, kacc = 0.f;

        // prologue: stage chunk 0 into buffer 0
        float4 nxt = h4[tid];
        hs[0][s0 + 0][dd_ld] = nxt.x;
        hs[0][s0 + 1][dd_ld] = nxt.y;
        hs[0][s0 + 2][dd_ld] = nxt.z;
        hs[0][s0 + 3][dd_ld] = nxt.w;
        __syncthreads();

        for (int c = 0; c < NCHUNK; ++c) {
            const int cur = c & 1;
            // prefetch next chunk (in flight across the compute below)
            if (c + 1 < NCHUNK) nxt = h4[(c + 1) * 256 + tid];

            const float* __restrict__ wq = wqp + c * CHUNK;
            const float* __restrict__ wk = wkp + c * CHUNK;
            const float* __restrict__ hrow = &hs[cur][s][0];
            #pragma unroll
            for (int dd = 0; dd < CHUNK; dd += 4) {
                float4 hv  = *(const float4*)(hrow + dd);
                float4 wq4 = *(const float4*)(wq + dd);
                float4 wk4 = *(const float4*)(wk + dd);
                qacc = fmaf(hv.x, wq4.x, qacc);
                qacc = fmaf(hv.y, wq4.y, qacc);
                qacc = fmaf(hv.z, wq4.z, qacc);
                qacc = fmaf(hv.w, wq4.w, qacc);
                kacc = fmaf(hv.x, wk4.x, kacc);
                kacc = fmaf(hv.y, wk4.y, kacc);
                kacc = fmaf(hv.z, wk4.z, kacc);
                kacc = fmaf(hv.w, wk4.w, kacc);
            }

            // stage next chunk into the other buffer (safe: readers of that
            // buffer finished at the barrier that ended the previous iter)
            if (c + 1 < NCHUNK) {
                const int nb = cur ^ 1;
                hs[nb][s0 + 0][dd_ld] = nxt.x;
                hs[nb][s0 + 1][dd_ld] = nxt.y;
                hs[nb][s0 + 2][dd_ld] = nxt.z;
                hs[nb][s0 + 3][dd_ld] = nxt.w;
            }
            __syncthreads();
        }

        Qs[s][a] = qacc;
        Ks[s][a] = kacc;
    }
    __syncthreads();

    // ---------------- Phase 2: scores + softmax + fold gate ----------------
    const float g = gate[0];
    {
        const int ss = tid >> 4;   // s (query slot)
        const int tt = tid & 15;   // t (key slot)
        float sc = 0.f;
        #pragma unroll
        for (int a4 = 0; a4 < 16; a4 += 4) {
            float4 qv = *(const float4*)&Qs[ss][a4];
            float4 kv = *(const float4*)&Ks[tt][a4];
            sc = fmaf(qv.x, kv.x, sc);
            sc = fmaf(qv.y, kv.y, sc);
            sc = fmaf(qv.z, kv.z, sc);
            sc = fmaf(qv.w, kv.w, sc);
        }
        sc *= 0.25f;  // D_ATTN^-0.5

        // softmax over tt within each 16-lane group (same ss)
        float m = sc;
        #pragma unroll
        for (int o = 8; o > 0; o >>= 1) m = fmaxf(m, __shfl_xor(m, o, 16));
        float e = __expf(sc - m);
        float sm = e;
        #pragma unroll
        for (int o = 8; o > 0; o >>= 1) sm += __shfl_xor(sm, o, 16);
        float attn = e / sm;

        // M[t][s] = delta(s,t) + g * attn[s][t]
        Ms[tt][ss] = ((ss == tt) ? 1.f : 0.f) + g * attn;
    }
    __syncthreads();

    // ---------------- Phase 3: out = H * M  (+residual folded in M) ------
    // thread: sq = tid&3 (s-quad), row = tid>>2 (+64 stride)
    {
        const int sq = tid & 3;
        const int r0 = tid >> 2;
        float4 M4[16];
        #pragma unroll
        for (int tp = 0; tp < 16; ++tp)
            M4[tp] = *(const float4*)&Ms[tp][sq * 4];

        for (int r = r0; r < DI; r += 64) {
            const float4* __restrict__ hr = (const float4*)(hbase + (size_t)r * DS);
            float4 ha = hr[0];
            float4 hc = hr[1];
            float4 he = hr[2];
            float4 hg = hr[3];
            float4 acc; acc.x = acc.y = acc.z = acc.w = 0.f;
            #define ACC4(hsc, mm) \
                acc.x = fmaf(hsc, mm.x, acc.x); \
                acc.y = fmaf(hsc, mm.y, acc.y); \
                acc.z = fmaf(hsc, mm.z, acc.z); \
                acc.w = fmaf(hsc, mm.w, acc.w);
            ACC4(ha.x, M4[0]);  ACC4(ha.y, M4[1]);
            ACC4(ha.z, M4[2]);  ACC4(ha.w, M4[3]);
            ACC4(hc.x, M4[4]);  ACC4(hc.y, M4[5]);
            ACC4(hc.z, M4[6]);  ACC4(hc.w, M4[7]);
            ACC4(he.x, M4[8]);  ACC4(he.y, M4[9]);
            ACC4(he.z, M4[10]); ACC4(he.w, M4[11]);
            ACC4(hg.x, M4[12]); ACC4(hg.y, M4[13]);
            ACC4(hg.z, M4[14]); ACC4(hg.w, M4[15]);
            #undef ACC4
            *(float4*)(obase + (size_t)r * DS + sq * 4) = acc;
        }
    }
}

extern "C" void kernel_launch(void* const* d_in, const int* in_sizes, int n_in,
                              void* d_out, int out_size, void* d_ws, size_t ws_size,
                              hipStream_t stream) {
    const float* h    = (const float*)d_in[0];
    const float* Wq   = (const float*)d_in[1];
    const float* Wk   = (const float*)d_in[2];
    const float* gate = (const float*)d_in[3];
    float* out = (float*)d_out;
    (void)in_sizes; (void)n_in; (void)out_size; (void)d_ws; (void)ws_size;

    ica_fused<<<1024, 256, 0, stream>>>(h, Wq, Wk, gate, out);
}

// Round 3
// 177.651 us; speedup vs baseline: 3.0595x; 2.5143x over previous
//
#include <hip/hip_runtime.h>
#include <hip/hip_bf16.h>

// IntraCellularAttention: B=1024, D_INNER=4096, D_STATE=16, D_ATTN=16
// out[b,d,s] = h[b,d,s] + gate * sum_t attn[b,s,t] * h[b,d,t]
// attn[s,t] = softmax_t( (Q K^T)[s,t] * 0.25 ),  Q[s,a] = sum_d h[b,d,s] Wq[a,d]
//
// Phase 1: Q,K via mfma_f32_16x16x32_bf16, one wave per 1024-d slice,
//          no LDS staging (A-frag loads are naturally coalesced dwords;
//          B-frag = W row slices, each W byte read once per wave from L2).
// Phase 2: 4-partial reduce + softmax, fold gate+identity into M.
// Phase 3: out = H * M, fp32 FMA, coalesced float4, 1-deep pipeline.

constexpr int DI = 4096;
constexpr int DS = 16;

typedef __attribute__((ext_vector_type(8))) short bf16x8;
typedef __attribute__((ext_vector_type(4))) float f32x4;

static __device__ __forceinline__ short f2bf(float x) {
    union { __hip_bfloat16 h; short s; } u;
    u.h = __float2bfloat16(x);
    return u.s;
}

__global__ __launch_bounds__(256, 4) void ica_fused(
    const float* __restrict__ h,
    const float* __restrict__ Wq,
    const float* __restrict__ Wk,
    const float* __restrict__ gate,
    float* __restrict__ out)
{
    const int b    = blockIdx.x;
    const int tid  = threadIdx.x;
    const int lane = tid & 63;
    const int wv   = tid >> 6;          // wave 0..3 -> d-quarter

    const float* __restrict__ hbase = h   + (size_t)b * (DI * DS);
    float*       __restrict__ obase = out + (size_t)b * (DI * DS);

    __shared__ float qp[4][16][20];     // per-wave Q partials [w][s][a]
    __shared__ float kp[4][16][20];
    __shared__ float Qs[DS][20];        // summed Q [s][a]
    __shared__ float Ks[DS][20];
    __shared__ float Ms[DS][20];        // [t][s] = delta(s,t) + g*attn[s][t]

    // ---------------- Phase 1: Q,K partials via MFMA (no barriers) --------
    {
        const int sa = lane & 15;       // s for A-frag rows / a for B-frag rows
        const int kb = lane >> 4;       // k-subblock 0..3 (8 elems each)
        f32x4 accQ = {0.f, 0.f, 0.f, 0.f};
        f32x4 accK = {0.f, 0.f, 0.f, 0.f};
        const int d0w = wv * (DI / 4);

        for (int it = 0; it < (DI / 4) / 32; ++it) {
            const int db = d0w + it * 32 + kb * 8;

            // A-frag: S[sa][db..db+7] = h[db+i][sa]  (coalesced dword loads)
            const float* __restrict__ hp = hbase + (size_t)db * DS + sa;
            float a0 = hp[0 * DS], a1 = hp[1 * DS], a2 = hp[2 * DS], a3 = hp[3 * DS];
            float a4 = hp[4 * DS], a5 = hp[5 * DS], a6 = hp[6 * DS], a7 = hp[7 * DS];

            // B-frags: Wq[sa][db..db+7], Wk[sa][db..db+7]  (L2-resident)
            const float* __restrict__ wqr = Wq + (size_t)sa * DI + db;
            const float* __restrict__ wkr = Wk + (size_t)sa * DI + db;
            float4 q0 = *(const float4*)(wqr);
            float4 q1 = *(const float4*)(wqr + 4);
            float4 k0 = *(const float4*)(wkr);
            float4 k1 = *(const float4*)(wkr + 4);

            bf16x8 af, bq, bk;
            af[0] = f2bf(a0);  af[1] = f2bf(a1);  af[2] = f2bf(a2);  af[3] = f2bf(a3);
            af[4] = f2bf(a4);  af[5] = f2bf(a5);  af[6] = f2bf(a6);  af[7] = f2bf(a7);
            bq[0] = f2bf(q0.x); bq[1] = f2bf(q0.y); bq[2] = f2bf(q0.z); bq[3] = f2bf(q0.w);
            bq[4] = f2bf(q1.x); bq[5] = f2bf(q1.y); bq[6] = f2bf(q1.z); bq[7] = f2bf(q1.w);
            bk[0] = f2bf(k0.x); bk[1] = f2bf(k0.y); bk[2] = f2bf(k0.z); bk[3] = f2bf(k0.w);
            bk[4] = f2bf(k1.x); bk[5] = f2bf(k1.y); bk[6] = f2bf(k1.z); bk[7] = f2bf(k1.w);

            accQ = __builtin_amdgcn_mfma_f32_16x16x32_bf16(af, bq, accQ, 0, 0, 0);
            accK = __builtin_amdgcn_mfma_f32_16x16x32_bf16(af, bk, accK, 0, 0, 0);
        }

        // D mapping (m89-verified): col = lane&15 (=a), row = (lane>>4)*4+reg (=s)
        #pragma unroll
        for (int r = 0; r < 4; ++r) {
            qp[wv][(lane >> 4) * 4 + r][lane & 15] = accQ[r];
            kp[wv][(lane >> 4) * 4 + r][lane & 15] = accK[r];
        }
    }
    __syncthreads();

    // ---------------- reduce the 4 wave partials --------------------------
    {
        const int s = tid >> 4, a = tid & 15;
        Qs[s][a] = qp[0][s][a] + qp[1][s][a] + qp[2][s][a] + qp[3][s][a];
        Ks[s][a] = kp[0][s][a] + kp[1][s][a] + kp[2][s][a] + kp[3][s][a];
    }
    __syncthreads();

    // ---------------- Phase 2: scores + softmax + fold gate ---------------
    const float g = gate[0];
    {
        const int ss = tid >> 4;   // s (query slot)
        const int tt = tid & 15;   // t (key slot)
        float sc = 0.f;
        #pragma unroll
        for (int a4 = 0; a4 < 16; a4 += 4) {
            float4 qv = *(const float4*)&Qs[ss][a4];
            float4 kv = *(const float4*)&Ks[tt][a4];
            sc = fmaf(qv.x, kv.x, sc);
            sc = fmaf(qv.y, kv.y, sc);
            sc = fmaf(qv.z, kv.z, sc);
            sc = fmaf(qv.w, kv.w, sc);
        }
        sc *= 0.25f;  // D_ATTN^-0.5

        float m = sc;
        #pragma unroll
        for (int o = 8; o > 0; o >>= 1) m = fmaxf(m, __shfl_xor(m, o, 16));
        float e = __expf(sc - m);
        float sm = e;
        #pragma unroll
        for (int o = 8; o > 0; o >>= 1) sm += __shfl_xor(sm, o, 16);
        float attn = e / sm;

        Ms[tt][ss] = ((ss == tt) ? 1.f : 0.f) + g * attn;
    }
    __syncthreads();

    // ---------------- Phase 3: out = H * M (+residual folded in M) --------
    {
        const int sq = tid & 3;
        const int r0 = tid >> 2;
        float4 M4[16];
        #pragma unroll
        for (int tp = 0; tp < 16; ++tp)
            M4[tp] = *(const float4*)&Ms[tp][sq * 4];

        // 1-deep software pipeline on the h row
        const float4* __restrict__ hr0 = (const float4*)(hbase + (size_t)r0 * DS);
        float4 c0 = hr0[0], c1 = hr0[1], c2 = hr0[2], c3 = hr0[3];

        for (int r = r0; r < DI; r += 64) {
            float4 n0, n1, n2, n3;
            if (r + 64 < DI) {
                const float4* __restrict__ hn = (const float4*)(hbase + (size_t)(r + 64) * DS);
                n0 = hn[0]; n1 = hn[1]; n2 = hn[2]; n3 = hn[3];
            }
            float4 acc; acc.x = acc.y = acc.z = acc.w = 0.f;
            #define ACC4(hsc, mm) \
                acc.x = fmaf(hsc, mm.x, acc.x); \
                acc.y = fmaf(hsc, mm.y, acc.y); \
                acc.z = fmaf(hsc, mm.z, acc.z); \
                acc.w = fmaf(hsc, mm.w, acc.w);
            ACC4(c0.x, M4[0]);  ACC4(c0.y, M4[1]);
            ACC4(c0.z, M4[2]);  ACC4(c0.w, M4[3]);
            ACC4(c1.x, M4[4]);  ACC4(c1.y, M4[5]);
            ACC4(c1.z, M4[6]);  ACC4(c1.w, M4[7]);
            ACC4(c2.x, M4[8]);  ACC4(c2.y, M4[9]);
            ACC4(c2.z, M4[10]); ACC4(c2.w, M4[11]);
            ACC4(c3.x, M4[12]); ACC4(c3.y, M4[13]);
            ACC4(c3.z, M4[14]); ACC4(c3.w, M4[15]);
            #undef ACC4
            *(float4*)(obase + (size_t)r * DS + sq * 4) = acc;
            c0 = n0; c1 = n1; c2 = n2; c3 = n3;
        }
    }
}

extern "C" void kernel_launch(void* const* d_in, const int* in_sizes, int n_in,
                              void* d_out, int out_size, void* d_ws, size_t ws_size,
                              hipStream_t stream) {
    const float* h    = (const float*)d_in[0];
    const float* Wq   = (const float*)d_in[1];
    const float* Wk   = (const float*)d_in[2];
    const float* gate = (const float*)d_in[3];
    float* out = (float*)d_out;
    (void)in_sizes; (void)n_in; (void)out_size; (void)d_ws; (void)ws_size;

    ica_fused<<<1024, 256, 0, stream>>>(h, Wq, Wk, gate, out);
}

// Round 4
// 160.136 us; speedup vs baseline: 3.3942x; 1.1094x over previous
//
#include <hip/hip_runtime.h>
#include <hip/hip_bf16.h>

// IntraCellularAttention: B=1024, D_INNER=4096, D_STATE=16, D_ATTN=16
// out[b,d,s] = h[b,d,s] + gate * sum_t attn[b,s,t] * h[b,d,t]
// attn[s,t] = softmax_t( (Q K^T)[s,t] * 0.25 ),  Q[s,a] = sum_d h[b,d,s] Wq[a,d]
//
// Phase 1: Q,K via mfma_f32_16x16x32_bf16, one wave per 1024-d slice,
//          3-slot software pipeline on the h (dword, coalesced-segment) and
//          W (float4, L2-resident) loads.
// Phase 2: 4-partial reduce + softmax, fold gate+identity into M.
// Phase 3: out = H*M, fp32 FMA, 2-slot pipeline, non-temporal stores.

constexpr int DI = 4096;
constexpr int DS = 16;

typedef __attribute__((ext_vector_type(8))) short bf16x8;
typedef __attribute__((ext_vector_type(4))) float f32x4;

static __device__ __forceinline__ short f2bf(float x) {
    union { __hip_bfloat16 h; short s; } u;
    u.h = __float2bfloat16(x);
    return u.s;
}

__global__ __launch_bounds__(256, 4) void ica_fused(
    const float* __restrict__ h,
    const float* __restrict__ Wq,
    const float* __restrict__ Wk,
    const float* __restrict__ gate,
    float* __restrict__ out)
{
    const int b    = blockIdx.x;
    const int tid  = threadIdx.x;
    const int lane = tid & 63;
    const int wv   = tid >> 6;          // wave 0..3 -> d-quarter

    const float* __restrict__ hbase = h   + (size_t)b * (DI * DS);
    float*       __restrict__ obase = out + (size_t)b * (DI * DS);

    __shared__ float qp[4][16][20];     // per-wave Q partials [w][s][a]
    __shared__ float kp[4][16][20];
    __shared__ float Qs[DS][20];        // summed Q [s][a]
    __shared__ float Ks[DS][20];
    __shared__ float Ms[DS][20];        // [t][s] = delta(s,t) + g*attn[s][t]

    // ---------------- Phase 1: Q,K partials via MFMA, 3-slot pipeline -----
    {
        const int sa  = lane & 15;      // s for A-frag rows / a for B-frag rows
        const int kb  = lane >> 4;      // k-subblock 0..3 (8 elems each)
        const int d0w = wv * (DI / 4);
        const float* __restrict__ wqb = Wq + (size_t)sa * DI;
        const float* __restrict__ wkb = Wk + (size_t)sa * DI;

        f32x4 accQ = {0.f, 0.f, 0.f, 0.f};
        f32x4 accK = {0.f, 0.f, 0.f, 0.f};

#define P1_LD(IT, A, Q0, Q1, K0, K1) do {                                   \
        const int db_ = d0w + (IT) * 32 + kb * 8;                           \
        const float* __restrict__ hp_ = hbase + (size_t)db_ * DS + sa;      \
        A[0] = hp_[0 * DS]; A[1] = hp_[1 * DS];                             \
        A[2] = hp_[2 * DS]; A[3] = hp_[3 * DS];                             \
        A[4] = hp_[4 * DS]; A[5] = hp_[5 * DS];                             \
        A[6] = hp_[6 * DS]; A[7] = hp_[7 * DS];                             \
        Q0 = *(const float4*)(wqb + db_); Q1 = *(const float4*)(wqb + db_ + 4); \
        K0 = *(const float4*)(wkb + db_); K1 = *(const float4*)(wkb + db_ + 4); \
    } while (0)

#define P1_FMA(A, Q0, Q1, K0, K1) do {                                      \
        bf16x8 af_, bq_, bk_;                                               \
        af_[0] = f2bf(A[0]); af_[1] = f2bf(A[1]);                           \
        af_[2] = f2bf(A[2]); af_[3] = f2bf(A[3]);                           \
        af_[4] = f2bf(A[4]); af_[5] = f2bf(A[5]);                           \
        af_[6] = f2bf(A[6]); af_[7] = f2bf(A[7]);                           \
        bq_[0] = f2bf(Q0.x); bq_[1] = f2bf(Q0.y);                           \
        bq_[2] = f2bf(Q0.z); bq_[3] = f2bf(Q0.w);                           \
        bq_[4] = f2bf(Q1.x); bq_[5] = f2bf(Q1.y);                           \
        bq_[6] = f2bf(Q1.z); bq_[7] = f2bf(Q1.w);                           \
        bk_[0] = f2bf(K0.x); bk_[1] = f2bf(K0.y);                           \
        bk_[2] = f2bf(K0.z); bk_[3] = f2bf(K0.w);                           \
        bk_[4] = f2bf(K1.x); bk_[5] = f2bf(K1.y);                           \
        bk_[6] = f2bf(K1.z); bk_[7] = f2bf(K1.w);                           \
        accQ = __builtin_amdgcn_mfma_f32_16x16x32_bf16(af_, bq_, accQ, 0, 0, 0); \
        accK = __builtin_amdgcn_mfma_f32_16x16x32_bf16(af_, bk_, accK, 0, 0, 0); \
    } while (0)

        float A0[8], A1[8], A2[8];
        float4 Q00, Q01, K00, K01;
        float4 Q10, Q11, K10, K11;
        float4 Q20, Q21, K20, K21;

        P1_LD(0, A0, Q00, Q01, K00, K01);
        P1_LD(1, A1, Q10, Q11, K10, K11);
        P1_LD(2, A2, Q20, Q21, K20, K21);

        // 32 iterations total; loop computes 0..29, tail computes 30,31.
        for (int it = 0; it < 30; it += 3) {
            P1_FMA(A0, Q00, Q01, K00, K01);
            P1_LD(it + 3, A0, Q00, Q01, K00, K01);
            P1_FMA(A1, Q10, Q11, K10, K11);
            P1_LD(it + 4, A1, Q10, Q11, K10, K11);
            P1_FMA(A2, Q20, Q21, K20, K21);
            if (it + 5 < 32) P1_LD(it + 5, A2, Q20, Q21, K20, K21);
        }
        P1_FMA(A0, Q00, Q01, K00, K01);   // iter 30
        P1_FMA(A1, Q10, Q11, K10, K11);   // iter 31

#undef P1_LD
#undef P1_FMA

        // D mapping (m89-verified): col = lane&15 (=a), row = (lane>>4)*4+reg (=s)
        #pragma unroll
        for (int r = 0; r < 4; ++r) {
            qp[wv][(lane >> 4) * 4 + r][lane & 15] = accQ[r];
            kp[wv][(lane >> 4) * 4 + r][lane & 15] = accK[r];
        }
    }
    __syncthreads();

    // ---------------- reduce the 4 wave partials --------------------------
    {
        const int s = tid >> 4, a = tid & 15;
        Qs[s][a] = qp[0][s][a] + qp[1][s][a] + qp[2][s][a] + qp[3][s][a];
        Ks[s][a] = kp[0][s][a] + kp[1][s][a] + kp[2][s][a] + kp[3][s][a];
    }
    __syncthreads();

    // ---------------- Phase 2: scores + softmax + fold gate ---------------
    const float g = gate[0];
    {
        const int ss = tid >> 4;   // s (query slot)
        const int tt = tid & 15;   // t (key slot)
        float sc = 0.f;
        #pragma unroll
        for (int a4 = 0; a4 < 16; a4 += 4) {
            float4 qv = *(const float4*)&Qs[ss][a4];
            float4 kv = *(const float4*)&Ks[tt][a4];
            sc = fmaf(qv.x, kv.x, sc);
            sc = fmaf(qv.y, kv.y, sc);
            sc = fmaf(qv.z, kv.z, sc);
            sc = fmaf(qv.w, kv.w, sc);
        }
        sc *= 0.25f;  // D_ATTN^-0.5

        float m = sc;
        #pragma unroll
        for (int o = 8; o > 0; o >>= 1) m = fmaxf(m, __shfl_xor(m, o, 16));
        float e = __expf(sc - m);
        float sm = e;
        #pragma unroll
        for (int o = 8; o > 0; o >>= 1) sm += __shfl_xor(sm, o, 16);
        float attn = e / sm;

        Ms[tt][ss] = ((ss == tt) ? 1.f : 0.f) + g * attn;
    }
    __syncthreads();

    // ---------------- Phase 3: out = H*M, 2-slot pipeline, nt stores ------
    {
        const int sq = tid & 3;
        const int r0 = tid >> 2;
        f32x4 M4[16];
        #pragma unroll
        for (int tp = 0; tp < 16; ++tp)
            M4[tp] = *(const f32x4*)&Ms[tp][sq * 4];

#define P3_LD(D, R) do {                                                    \
        const f32x4* __restrict__ hr_ = (const f32x4*)(hbase + (size_t)(R) * DS); \
        D##0 = hr_[0]; D##1 = hr_[1]; D##2 = hr_[2]; D##3 = hr_[3];         \
    } while (0)

#define AC4(hsc, MM)                                                        \
        acc[0] = fmaf(hsc, (MM)[0], acc[0]);                                \
        acc[1] = fmaf(hsc, (MM)[1], acc[1]);                                \
        acc[2] = fmaf(hsc, (MM)[2], acc[2]);                                \
        acc[3] = fmaf(hsc, (MM)[3], acc[3]);

#define P3_ACC(S, R) do {                                                   \
        f32x4 acc = {0.f, 0.f, 0.f, 0.f};                                   \
        AC4(S##0[0], M4[0])  AC4(S##0[1], M4[1])                            \
        AC4(S##0[2], M4[2])  AC4(S##0[3], M4[3])                            \
        AC4(S##1[0], M4[4])  AC4(S##1[1], M4[5])                            \
        AC4(S##1[2], M4[6])  AC4(S##1[3], M4[7])                            \
        AC4(S##2[0], M4[8])  AC4(S##2[1], M4[9])                            \
        AC4(S##2[2], M4[10]) AC4(S##2[3], M4[11])                           \
        AC4(S##3[0], M4[12]) AC4(S##3[1], M4[13])                           \
        AC4(S##3[2], M4[14]) AC4(S##3[3], M4[15])                           \
        __builtin_nontemporal_store(acc, (f32x4*)(obase + (size_t)(R) * DS + sq * 4)); \
    } while (0)

        f32x4 cA0, cA1, cA2, cA3;
        f32x4 cB0, cB1, cB2, cB3;
        P3_LD(cA, r0);
        P3_LD(cB, r0 + 64);

        for (int r = r0; r < DI; r += 128) {
            P3_ACC(cA, r);
            if (r + 128 < DI) P3_LD(cA, r + 128);   // uniform guard
            P3_ACC(cB, r + 64);
            if (r + 192 < DI) P3_LD(cB, r + 192);   // uniform guard
        }
#undef P3_LD
#undef P3_ACC
#undef AC4
    }
}

extern "C" void kernel_launch(void* const* d_in, const int* in_sizes, int n_in,
                              void* d_out, int out_size, void* d_ws, size_t ws_size,
                              hipStream_t stream) {
    const float* h    = (const float*)d_in[0];
    const float* Wq   = (const float*)d_in[1];
    const float* Wk   = (const float*)d_in[2];
    const float* gate = (const float*)d_in[3];
    float* out = (float*)d_out;
    (void)in_sizes; (void)n_in; (void)out_size; (void)d_ws; (void)ws_size;

    ica_fused<<<1024, 256, 0, stream>>>(h, Wq, Wk, gate, out);
}